// Round 6
// baseline (260.051 us; speedup 1.0000x reference)
//
#include <hip/hip_runtime.h>
#include <math.h>

// Workspace layout (floats):
//   [0,256)          T     : full symmetric Re(U^H M U)
//   [256,800)        S     : atomic-fallback accumulators S[b][q]
//   [800,832)        n     : atomic-fallback squared norms
//   [832]            ctr   : block completion counter (int)
//   [1024,35840)     Spart : partials [b][q][chunk]  32*17*64
//   [35840,37888)    npart : norm partials [b][chunk] 32*64
#define WS_TU    0
#define WS_S     256
#define WS_N     800
#define WS_CTR   832
#define WS_PART  1024
#define WS_NPART 35840
#define WS_NEED_BYTES ((WS_NPART + 2048) * 4)

typedef _Float16 half8 __attribute__((ext_vector_type(8)));
typedef float f32x4 __attribute__((ext_vector_type(4)));

__device__ inline float2 cmul2(float2 a, float2 b) {
  return make_float2(a.x * b.x - a.y * b.y, a.x * b.y + a.y * b.x);
}

__device__ inline int ringperm(int x) {
  if ((x >> 3) & 1) x ^= 4;
  if ((x >> 2) & 1) x ^= 2;
  if ((x >> 1) & 1) x ^= 1;
  if (x & 1)        x ^= 8;
  return x;
}

__device__ inline float2 yzy_elem(const float* wgt, int layer, int r, int c) {
  float2 prod = make_float2(1.f, 0.f);
#pragma unroll
  for (int k = 0; k < 4; k++) {
    float t0 = wgt[layer * 12 + 3 * k + 0];
    float t1 = wgt[layer * 12 + 3 * k + 1];
    float t2 = wgt[layer * 12 + 3 * k + 2];
    float s0, c0, s1, c1, s2, c2;
    sincosf(0.5f * t0, &s0, &c0);
    sincosf(0.5f * t1, &s1, &c1);
    sincosf(0.5f * t2, &s2, &c2);
    float A = c2 * c0, B = s2 * s0, C = c2 * s0, D = s2 * c0;
    float2 m00 = make_float2( c1 * (A - B), -s1 * (A + B));
    float2 m01 = make_float2(-c1 * (C + D),  s1 * (C - D));
    float2 m10 = make_float2( c1 * (C + D),  s1 * (C - D));
    float2 m11 = make_float2( c1 * (A - B),  s1 * (A + B));
    int rb = (r >> (3 - k)) & 1, cb = (c >> (3 - k)) & 1;
    float2 mm = rb ? (cb ? m11 : m10) : (cb ? m01 : m00);
    prod = cmul2(prod, mm);
  }
  return prod;
}

__global__ void build_T_kernel(const float* __restrict__ wgt, float* __restrict__ ws) {
  __shared__ float2 U[256], Y[256], W[256];
  const int t = threadIdx.x;
  const int r = t >> 4, c = t & 15;

  // zero the atomic-fallback accumulators and the completion counter
  for (int k = t; k < 576; k += 256) ws[WS_S + k] = 0.f;
  if (t == 0) *(int*)(ws + WS_CTR) = 0;

  U[t] = yzy_elem(wgt, 0, r, c);
  __syncthreads();
  W[ringperm(r) * 16 + c] = U[t];
  __syncthreads(); U[t] = W[t]; __syncthreads();
  Y[t] = yzy_elem(wgt, 1, r, c);
  __syncthreads();
  {
    float2 s = make_float2(0.f, 0.f);
#pragma unroll
    for (int k = 0; k < 16; k++) {
      float2 pr = cmul2(Y[r * 16 + k], U[k * 16 + c]);
      s.x += pr.x; s.y += pr.y;
    }
    W[t] = s;
  }
  __syncthreads(); U[t] = W[t]; __syncthreads();
  W[ringperm(r) * 16 + c] = U[t];
  __syncthreads(); U[t] = W[t]; __syncthreads();
  Y[t] = yzy_elem(wgt, 2, r, c);
  __syncthreads();
  {
    float2 s = make_float2(0.f, 0.f);
#pragma unroll
    for (int k = 0; k < 16; k++) {
      float2 pr = cmul2(Y[r * 16 + k], U[k * 16 + c]);
      s.x += pr.x; s.y += pr.y;
    }
    W[t] = s;
  }
  __syncthreads(); U[t] = W[t]; __syncthreads();
  Y[t] = U[(r ^ 15) * 16 + c];
  __syncthreads();
  float s_re = 0.f;
#pragma unroll
  for (int k = 0; k < 16; k++) {
    float2 u = U[k * 16 + r], m = Y[k * 16 + c];
    s_re += u.x * m.x + u.y * m.y;
  }
  ws[WS_TU + t] = s_re;  // full symmetric T
}

// XOR-fold swizzle on 16B-block index
__device__ inline int swzB(int B) {
  int h = B >> 3;
  int f = (h ^ (h >> 3) ^ (h >> 6)) & 7;
  return B ^ f;
}

// Gram-window via MFMA, dual accumulator chains for ILP.
// LDS: 2048 16B blocks of 8 f16, block index swizzled. i-field at pos bits [P,P+4).
template <int P>
__device__ inline float windowM(const half8* __restrict__ HB, const float* __restrict__ Tr) {
  const int t = threadIdx.x;
  const int w = t >> 6, l = t & 63, g = l >> 4, i = l & 15;
  f32x4 h0 = {0.f, 0.f, 0.f, 0.f}, h1 = {0.f, 0.f, 0.f, 0.f};
#pragma unroll
  for (int s = 0; s < 4; s++) {
    int rest0 = (w << 5) | (s << 2) | g;        // 7-bit rest, chain 0
    int rest1 = (w << 5) | ((s + 4) << 2) | g;  // chain 1
    int rl0 = rest0 & ((1 << (P - 3)) - 1), rh0 = rest0 >> (P - 3);
    int rl1 = rest1 & ((1 << (P - 3)) - 1), rh1 = rest1 >> (P - 3);
    int pos0 = (rl0 << 3) | (i << P) | (rh0 << (P + 4));
    int pos1 = (rl1 << 3) | (i << P) | (rh1 << (P + 4));
    half8 f0 = HB[swzB(pos0 >> 3)];
    half8 f1 = HB[swzB(pos1 >> 3)];
    h0 = __builtin_amdgcn_mfma_f32_16x16x32_f16(f0, f0, h0, 0, 0, 0);
    h1 = __builtin_amdgcn_mfma_f32_16x16x32_f16(f1, f1, h1, 0, 0, 0);
  }
  float part = 0.f;
#pragma unroll
  for (int reg = 0; reg < 4; reg++) part = fmaf(Tr[reg], h0[reg] + h1[reg], part);
  return part;
}

// modes: 0 = contiguous chunk: image0 (identity, p=3..10) then in-register
//            transpose -> image1 (rot+3, p=0,1,2), plus norms. ONE global read.
//        2 = strided row tile (p=11..16).
// blockIdx remap: batch b pinned to XCD b%8 (4 MB batch == 4 MB XCD L2);
// mode-0/mode-2 interleaved so both roles co-resident (L2 share + phase stagger).
__global__ __launch_bounds__(256) void passAll_kernel(const float* __restrict__ vb,
                                                      float* ws, float* __restrict__ out,
                                                      int use_part) {
  __shared__ half8 HB[2048];   // exactly 32 KB; reduce scratch aliases it later
  __shared__ int lastflag;
  const int t = threadIdx.x;

  const int xcd = blockIdx.x & 7;
  const int slot = blockIdx.x >> 3;          // [0,512) per XCD
  const int lb = slot >> 7;                  // 4 batches per XCD
  const int w127 = slot & 127;
  const int mode = (w127 & 1) ? 2 : 0;
  const int chunk = w127 >> 1;               // [0,64)
  const int b = lb * 8 + xcd;
  const int l = t & 63, g = l >> 4, i = l & 15;

  // per-thread T values: T[g*4+reg][i] is all this lane ever needs
  float Treg[4];
#pragma unroll
  for (int reg = 0; reg < 4; reg++) Treg[reg] = ws[WS_TU + ((g * 4 + reg) << 4) + i];

  float nsum = 0.f;
  half8 h[8];  // mode 0: staged data kept in registers for the image1 transpose
  if (mode == 0) {
    const float4* src4 = ((const float4*)vb) + ((size_t)b << 18) + ((size_t)chunk << 12);
#pragma unroll
    for (int j = 0; j < 8; j++) {
      int B = j * 256 + t;
      float4 a = src4[2 * B], c = src4[2 * B + 1];
      nsum = fmaf(a.x, a.x, nsum); nsum = fmaf(a.y, a.y, nsum);
      nsum = fmaf(a.z, a.z, nsum); nsum = fmaf(a.w, a.w, nsum);
      nsum = fmaf(c.x, c.x, nsum); nsum = fmaf(c.y, c.y, nsum);
      nsum = fmaf(c.z, c.z, nsum); nsum = fmaf(c.w, c.w, nsum);
      half8 hh;
      hh[0] = (_Float16)a.x; hh[1] = (_Float16)a.y; hh[2] = (_Float16)a.z; hh[3] = (_Float16)a.w;
      hh[4] = (_Float16)c.x; hh[5] = (_Float16)c.y; hh[6] = (_Float16)c.z; hh[7] = (_Float16)c.w;
      h[j] = hh;
      HB[swzB(B)] = hh;
    }
  } else {
    // tile: 32 consecutive floats x 512 rows at stride 2048 floats
    const float4* src4 = ((const float4*)vb) + ((size_t)b << 18) + chunk * 8;
#pragma unroll
    for (int j = 0; j < 8; j++) {
      int B = j * 256 + t;
      int row = B >> 2;
      int c4 = (B & 3) * 2;
      float4 a = src4[row * 512 + c4], c = src4[row * 512 + c4 + 1];
      half8 hh;
      hh[0] = (_Float16)a.x; hh[1] = (_Float16)a.y; hh[2] = (_Float16)a.z; hh[3] = (_Float16)a.w;
      hh[4] = (_Float16)c.x; hh[5] = (_Float16)c.y; hh[6] = (_Float16)c.z; hh[7] = (_Float16)c.w;
      HB[swzB(B)] = hh;
    }
  }
  __syncthreads();

  float part[11];
#pragma unroll
  for (int k = 0; k < 11; k++) part[k] = 0.f;

  int nwin;
#define DOWIN(P, WIN) part[WIN] = windowM<P>(HB, Treg);
  if (mode == 0) {
    nwin = 11;
    // image0: p = P, q = 16 - p  -> win 0..7 <-> q 13..6
    DOWIN(3, 0) DOWIN(4, 1) DOWIN(5, 2) DOWIN(6, 3)
    DOWIN(7, 4) DOWIN(8, 5) DOWIN(9, 6) DOWIN(10, 7)
    __syncthreads();  // all image0 reads done
    // image1 (rot+3): element x[2048u + c] -> pos = c*8 + u.
#pragma unroll
    for (int e = 0; e < 8; e++) {
      half8 v;
#pragma unroll
      for (int j = 0; j < 8; j++) v[j] = h[j][e];
      HB[swzB(8 * t + e)] = v;
    }
    __syncthreads();
    // image1: p = P - 3 in {0,1,2} -> win 8,9,10 <-> q 16,15,14
    DOWIN(3, 8) DOWIN(4, 9) DOWIN(5, 10)
  } else {
    nwin = 6;
    // p = P + 6 in {11..16} -> win 0..5 <-> q 5..0
    DOWIN(5, 0) DOWIN(6, 1) DOWIN(7, 2)
    DOWIN(8, 3) DOWIN(9, 4) DOWIN(10, 5)
  }
#undef DOWIN
  __syncthreads();  // all reads of HB done; safe to alias reduce scratch

  float* red2 = (float*)HB;  // 12*256 floats = 12 KB
#pragma unroll
  for (int k = 0; k < 11; k++) red2[k * 256 + t] = part[k];
  red2[11 * 256 + t] = nsum;
  __syncthreads();

  // batched cross-block reduction: 16-thread group per value (12 live groups)
  const int win = t >> 4, idx16 = t & 15;
  const float4* r4 = (const float4*)red2;
  float4 q0 = r4[win * 64 + idx16],      q1 = r4[win * 64 + 16 + idx16];
  float4 q2 = r4[win * 64 + 32 + idx16], q3 = r4[win * 64 + 48 + idx16];
  float s1 = ((q0.x + q0.y) + (q0.z + q0.w)) + ((q1.x + q1.y) + (q1.z + q1.w)) +
             ((q2.x + q2.y) + (q2.z + q2.w)) + ((q3.x + q3.y) + (q3.z + q3.w));
#pragma unroll
  for (int off = 8; off; off >>= 1) s1 += __shfl_down(s1, off, 16);

  if (idx16 == 0) {
    if (mode == 0) {
      if (win < 11) {
        int q = (win < 8) ? (13 - win) : (24 - win);
        if (use_part) ws[WS_PART + (b * 17 + q) * 64 + chunk] = s1;
        else          atomicAdd(ws + WS_S + b * 17 + q, s1);
      } else if (win == 11) {
        if (use_part) ws[WS_NPART + b * 64 + chunk] = s1;
        else          atomicAdd(ws + WS_N + b, s1);
      }
    } else {
      if (win < 6) {
        int q = 5 - win;
        if (use_part) ws[WS_PART + (b * 17 + q) * 64 + chunk] = s1;
        else          atomicAdd(ws + WS_S + b * 17 + q, s1);
      }
    }
  }

  // ---- last block finalizes (release/acquire via device-scope atomic) ----
  if (t == 0) {
    __threadfence();
    int old = __hip_atomic_fetch_add((int*)(ws + WS_CTR), 1,
                                     __ATOMIC_ACQ_REL, __HIP_MEMORY_SCOPE_AGENT);
    lastflag = (old == 4095);
  }
  __syncthreads();
  if (lastflag) {
    __threadfence();
    for (int i2 = t; i2 < 544; i2 += 256) {
      int b2 = i2 / 17;
      float s, n;
      if (use_part) {
        const float* sp = ws + WS_PART + i2 * 64;
        s = 0.f;
#pragma unroll 8
        for (int c = 0; c < 64; c++) s += sp[c];
        const float* np = ws + WS_NPART + b2 * 64;
        n = 0.f;
#pragma unroll 8
        for (int c = 0; c < 64; c++) n += np[c];
      } else {
        s = ws[WS_S + i2];
        n = ws[WS_N + b2];
      }
      out[i2] = s / fmaxf(n, 1e-24f);
    }
  }
}

extern "C" void kernel_launch(void* const* d_in, const int* in_sizes, int n_in,
                              void* d_out, int out_size, void* d_ws, size_t ws_size,
                              hipStream_t stream) {
  const float* vb  = (const float*)d_in[0];
  const float* wgt = (const float*)d_in[1];
  float* out = (float*)d_out;
  float* ws  = (float*)d_ws;
  int use_part = (ws_size >= (size_t)WS_NEED_BYTES) ? 1 : 0;

  build_T_kernel<<<1, 256, 0, stream>>>(wgt, ws);
  passAll_kernel<<<4096, 256, 0, stream>>>(vb, ws, out, use_part);
}

// Round 7
// 59.109 us; speedup vs baseline: 4.3995x; 4.3995x over previous
//
#include <hip/hip_runtime.h>
#include <math.h>

// Workspace layout (floats):
//   [0,256)          T     : full symmetric Re(U^H M U)
//   [256,800)        S     : atomic-fallback accumulators S[b][q]
//   [800,832)        n     : atomic-fallback squared norms
//   [1024,35840)     Spart : partials [b][q][chunk]  32*17*64
//   [35840,37888)    npart : norm partials [b][chunk] 32*64
#define WS_TU    0
#define WS_S     256
#define WS_N     800
#define WS_PART  1024
#define WS_NPART 35840
#define WS_NEED_BYTES ((WS_NPART + 2048) * 4)

typedef _Float16 half8 __attribute__((ext_vector_type(8)));
typedef float f32x4 __attribute__((ext_vector_type(4)));

__device__ inline float2 cmul2(float2 a, float2 b) {
  return make_float2(a.x * b.x - a.y * b.y, a.x * b.y + a.y * b.x);
}

__device__ inline int ringperm(int x) {
  if ((x >> 3) & 1) x ^= 4;
  if ((x >> 2) & 1) x ^= 2;
  if ((x >> 1) & 1) x ^= 1;
  if (x & 1)        x ^= 8;
  return x;
}

__device__ inline float2 yzy_elem(const float* wgt, int layer, int r, int c) {
  float2 prod = make_float2(1.f, 0.f);
#pragma unroll
  for (int k = 0; k < 4; k++) {
    float t0 = wgt[layer * 12 + 3 * k + 0];
    float t1 = wgt[layer * 12 + 3 * k + 1];
    float t2 = wgt[layer * 12 + 3 * k + 2];
    float s0, c0, s1, c1, s2, c2;
    sincosf(0.5f * t0, &s0, &c0);
    sincosf(0.5f * t1, &s1, &c1);
    sincosf(0.5f * t2, &s2, &c2);
    float A = c2 * c0, B = s2 * s0, C = c2 * s0, D = s2 * c0;
    float2 m00 = make_float2( c1 * (A - B), -s1 * (A + B));
    float2 m01 = make_float2(-c1 * (C + D),  s1 * (C - D));
    float2 m10 = make_float2( c1 * (C + D),  s1 * (C - D));
    float2 m11 = make_float2( c1 * (A - B),  s1 * (A + B));
    int rb = (r >> (3 - k)) & 1, cb = (c >> (3 - k)) & 1;
    float2 mm = rb ? (cb ? m11 : m10) : (cb ? m01 : m00);
    prod = cmul2(prod, mm);
  }
  return prod;
}

__global__ void build_T_kernel(const float* __restrict__ wgt, float* __restrict__ ws) {
  __shared__ float2 U[256], Y[256], W[256];
  const int t = threadIdx.x;
  const int r = t >> 4, c = t & 15;

  // zero the atomic-fallback accumulators (no separate memset dispatch)
  for (int k = t; k < 576; k += 256) ws[WS_S + k] = 0.f;

  U[t] = yzy_elem(wgt, 0, r, c);
  __syncthreads();
  W[ringperm(r) * 16 + c] = U[t];
  __syncthreads(); U[t] = W[t]; __syncthreads();
  Y[t] = yzy_elem(wgt, 1, r, c);
  __syncthreads();
  {
    float2 s = make_float2(0.f, 0.f);
#pragma unroll
    for (int k = 0; k < 16; k++) {
      float2 pr = cmul2(Y[r * 16 + k], U[k * 16 + c]);
      s.x += pr.x; s.y += pr.y;
    }
    W[t] = s;
  }
  __syncthreads(); U[t] = W[t]; __syncthreads();
  W[ringperm(r) * 16 + c] = U[t];
  __syncthreads(); U[t] = W[t]; __syncthreads();
  Y[t] = yzy_elem(wgt, 2, r, c);
  __syncthreads();
  {
    float2 s = make_float2(0.f, 0.f);
#pragma unroll
    for (int k = 0; k < 16; k++) {
      float2 pr = cmul2(Y[r * 16 + k], U[k * 16 + c]);
      s.x += pr.x; s.y += pr.y;
    }
    W[t] = s;
  }
  __syncthreads(); U[t] = W[t]; __syncthreads();
  Y[t] = U[(r ^ 15) * 16 + c];
  __syncthreads();
  float s_re = 0.f;
#pragma unroll
  for (int k = 0; k < 16; k++) {
    float2 u = U[k * 16 + r], m = Y[k * 16 + c];
    s_re += u.x * m.x + u.y * m.y;
  }
  ws[WS_TU + t] = s_re;  // full symmetric T
}

// XOR-fold swizzle on 16B-block index
__device__ inline int swzB(int B) {
  int h = B >> 3;
  int f = (h ^ (h >> 3) ^ (h >> 6)) & 7;
  return B ^ f;
}

// Gram-window via MFMA, FOUR accumulator chains of depth 2 (MFMA-latency hiding).
// LDS: 2048 16B blocks of 8 f16, block index swizzled. i-field at pos bits [P,P+4).
template <int P>
__device__ inline float windowM(const half8* __restrict__ HB, const float* __restrict__ Tr) {
  const int t = threadIdx.x;
  const int w = t >> 6, l = t & 63, g = l >> 4, i = l & 15;
  f32x4 hh[4] = {{0.f, 0.f, 0.f, 0.f}, {0.f, 0.f, 0.f, 0.f},
                 {0.f, 0.f, 0.f, 0.f}, {0.f, 0.f, 0.f, 0.f}};
#pragma unroll
  for (int s = 0; s < 2; s++) {
#pragma unroll
    for (int c = 0; c < 4; c++) {
      int rest = (w << 5) | ((s * 4 + c) << 2) | g;  // 7-bit rest
      int rl = rest & ((1 << (P - 3)) - 1), rh = rest >> (P - 3);
      int pos = (rl << 3) | (i << P) | (rh << (P + 4));
      half8 fr = HB[swzB(pos >> 3)];
      hh[c] = __builtin_amdgcn_mfma_f32_16x16x32_f16(fr, fr, hh[c], 0, 0, 0);
    }
  }
  float part = 0.f;
#pragma unroll
  for (int reg = 0; reg < 4; reg++)
    part = fmaf(Tr[reg], (hh[0][reg] + hh[1][reg]) + (hh[2][reg] + hh[3][reg]), part);
  return part;
}

// modes: 0 = contiguous chunk: image0 (identity, p=3..10) then in-register
//            transpose -> image1 (rot+3, p=0,1,2), plus norms. ONE global read.
//        2 = strided row tile (p=11..16), runs in the grid tail (L3-warm).
__global__ __launch_bounds__(256) void passAll_kernel(const float* __restrict__ vb,
                                                      float* ws, int use_part) {
  __shared__ half8 HB[2048];   // exactly 32 KB; reduce scratch aliases it later
  const int t = threadIdx.x;
  const int bid = blockIdx.x;

  const int mode = (bid < 2048) ? 0 : 2;
  const int idx = (bid < 2048) ? bid : bid - 2048;
  const int b = idx >> 6, chunk = idx & 63;
  const int l = t & 63, g = l >> 4, i = l & 15;

  // per-thread T values: T[g*4+reg][i] is all this lane ever needs
  float Treg[4];
#pragma unroll
  for (int reg = 0; reg < 4; reg++) Treg[reg] = ws[WS_TU + ((g * 4 + reg) << 4) + i];

  float nsum = 0.f;
  half8 h[8];  // mode 0: staged data kept in registers for the image1 transpose
  if (mode == 0) {
    const float4* src4 = ((const float4*)vb) + ((size_t)b << 18) + ((size_t)chunk << 12);
#pragma unroll
    for (int j = 0; j < 8; j++) {
      int B = j * 256 + t;
      float4 a = src4[2 * B], c = src4[2 * B + 1];
      nsum = fmaf(a.x, a.x, nsum); nsum = fmaf(a.y, a.y, nsum);
      nsum = fmaf(a.z, a.z, nsum); nsum = fmaf(a.w, a.w, nsum);
      nsum = fmaf(c.x, c.x, nsum); nsum = fmaf(c.y, c.y, nsum);
      nsum = fmaf(c.z, c.z, nsum); nsum = fmaf(c.w, c.w, nsum);
      half8 hh;
      hh[0] = (_Float16)a.x; hh[1] = (_Float16)a.y; hh[2] = (_Float16)a.z; hh[3] = (_Float16)a.w;
      hh[4] = (_Float16)c.x; hh[5] = (_Float16)c.y; hh[6] = (_Float16)c.z; hh[7] = (_Float16)c.w;
      h[j] = hh;
      HB[swzB(B)] = hh;
    }
  } else {
    // tile: 32 consecutive floats x 512 rows at stride 2048 floats
    const float4* src4 = ((const float4*)vb) + ((size_t)b << 18) + chunk * 8;
#pragma unroll
    for (int j = 0; j < 8; j++) {
      int B = j * 256 + t;
      int row = B >> 2;
      int c4 = (B & 3) * 2;
      float4 a = src4[row * 512 + c4], c = src4[row * 512 + c4 + 1];
      half8 hh;
      hh[0] = (_Float16)a.x; hh[1] = (_Float16)a.y; hh[2] = (_Float16)a.z; hh[3] = (_Float16)a.w;
      hh[4] = (_Float16)c.x; hh[5] = (_Float16)c.y; hh[6] = (_Float16)c.z; hh[7] = (_Float16)c.w;
      HB[swzB(B)] = hh;
    }
  }
  __syncthreads();

  float part[11];
#pragma unroll
  for (int k = 0; k < 11; k++) part[k] = 0.f;

  int nwin;
#define DOWIN(P, WIN) part[WIN] = windowM<P>(HB, Treg);
  if (mode == 0) {
    nwin = 11;
    // image0: p = P, q = 16 - p  -> win 0..7 <-> q 13..6
    DOWIN(3, 0) DOWIN(4, 1) DOWIN(5, 2) DOWIN(6, 3)
    DOWIN(7, 4) DOWIN(8, 5) DOWIN(9, 6) DOWIN(10, 7)
    __syncthreads();  // all image0 reads done
    // image1 (rot+3): element x[2048u + c] -> pos = c*8 + u.
    // Thread t holds h[j][e] = x[2048j + 8t + e]; block c = 8t+e gets {h[j][e]}_j.
#pragma unroll
    for (int e = 0; e < 8; e++) {
      half8 v;
#pragma unroll
      for (int j = 0; j < 8; j++) v[j] = h[j][e];
      HB[swzB(8 * t + e)] = v;
    }
    __syncthreads();
    // image1: p = P - 3 in {0,1,2} -> win 8,9,10 <-> q 16,15,14
    DOWIN(3, 8) DOWIN(4, 9) DOWIN(5, 10)
  } else {
    nwin = 6;
    // p = P + 6 in {11..16} -> win 0..5 <-> q 5..0
    DOWIN(5, 0) DOWIN(6, 1) DOWIN(7, 2)
    DOWIN(8, 3) DOWIN(9, 4) DOWIN(10, 5)
  }
#undef DOWIN
  __syncthreads();  // all reads of HB done; safe to alias reduce scratch

  float* red2 = (float*)HB;  // 12*256 floats = 12 KB
#pragma unroll
  for (int k = 0; k < 11; k++) red2[k * 256 + t] = part[k];
  red2[11 * 256 + t] = nsum;
  __syncthreads();

  // batched cross-block reduction: 16-thread group per value (12 live groups)
  const int win = t >> 4, idx16 = t & 15;
  const float4* r4 = (const float4*)red2;
  float4 q0 = r4[win * 64 + idx16],      q1 = r4[win * 64 + 16 + idx16];
  float4 q2 = r4[win * 64 + 32 + idx16], q3 = r4[win * 64 + 48 + idx16];
  float s1 = ((q0.x + q0.y) + (q0.z + q0.w)) + ((q1.x + q1.y) + (q1.z + q1.w)) +
             ((q2.x + q2.y) + (q2.z + q2.w)) + ((q3.x + q3.y) + (q3.z + q3.w));
#pragma unroll
  for (int off = 8; off; off >>= 1) s1 += __shfl_down(s1, off, 16);

  if (idx16 == 0) {
    if (mode == 0) {
      if (win < 11) {
        int q = (win < 8) ? (13 - win) : (24 - win);
        if (use_part) ws[WS_PART + (b * 17 + q) * 64 + chunk] = s1;
        else          atomicAdd(ws + WS_S + b * 17 + q, s1);
      } else if (win == 11) {
        if (use_part) ws[WS_NPART + b * 64 + chunk] = s1;
        else          atomicAdd(ws + WS_N + b, s1);
      }
    } else {
      if (win < 6) {
        int q = 5 - win;
        if (use_part) ws[WS_PART + (b * 17 + q) * 64 + chunk] = s1;
        else          atomicAdd(ws + WS_S + b * 17 + q, s1);
      }
    }
  }
}

__global__ void finalize_kernel(const float* __restrict__ ws, float* __restrict__ out,
                                int use_part) {
  int i = blockIdx.x * 256 + threadIdx.x;
  if (i < 544) {
    int b = i / 17;
    float s, n;
    if (use_part) {
      const float* sp = ws + WS_PART + i * 64;
      s = 0.f;
#pragma unroll 8
      for (int c = 0; c < 64; c++) s += sp[c];
      const float* np = ws + WS_NPART + b * 64;
      n = 0.f;
#pragma unroll 8
      for (int c = 0; c < 64; c++) n += np[c];
    } else {
      s = ws[WS_S + i];
      n = ws[WS_N + b];
    }
    out[i] = s / fmaxf(n, 1e-24f);
  }
}

extern "C" void kernel_launch(void* const* d_in, const int* in_sizes, int n_in,
                              void* d_out, int out_size, void* d_ws, size_t ws_size,
                              hipStream_t stream) {
  const float* vb  = (const float*)d_in[0];
  const float* wgt = (const float*)d_in[1];
  float* out = (float*)d_out;
  float* ws  = (float*)d_ws;
  int use_part = (ws_size >= (size_t)WS_NEED_BYTES) ? 1 : 0;

  build_T_kernel<<<1, 256, 0, stream>>>(wgt, ws);
  passAll_kernel<<<4096, 256, 0, stream>>>(vb, ws, use_part);
  finalize_kernel<<<3, 256, 0, stream>>>(ws, out, use_part);
}